// Round 1
// baseline (6534.959 us; speedup 1.0000x reference)
//
#include <hip/hip_runtime.h>

#define N_NODES 2048
#define KSEL 50

// ---- order-preserving fp32 <-> uint map (monotone: bigger float => bigger uint)
__device__ __forceinline__ unsigned ford(float f) {
  unsigned b = __float_as_uint(f);
  return b ^ ((b & 0x80000000u) ? 0xFFFFFFFFu : 0x80000000u);
}
__device__ __forceinline__ float funord(unsigned u) {
  unsigned b = (u & 0x80000000u) ? (u ^ 0x80000000u) : ~u;
  return __uint_as_float(b);
}

// out[row][c] = relu(bias[c] + sum_k in[row][k] * W[k][c]); 64 rows per block, 256 thr.
__global__ __launch_bounds__(256) void linrelu_kernel(
    const float* __restrict__ in, const float* __restrict__ W,
    const float* __restrict__ bias, float* __restrict__ out)
{
  const int tid = threadIdx.x;
  const size_t rowbase = (size_t)blockIdx.x * 64;
  __shared__ float xs[64 * 65];   // +1 pad: conflict-free lane-per-row reads
  __shared__ float Ws[64 * 64];
  __shared__ float bs[64];
#pragma unroll
  for (int i = 0; i < 16; ++i) {
    int idx = tid + 256 * i;
    xs[(idx >> 6) * 65 + (idx & 63)] = in[rowbase * 64 + idx];
    Ws[idx] = W[idx];
  }
  if (tid < 64) bs[tid] = bias[tid];
  __syncthreads();
  const int r = tid & 63;    // lane-per-row
  const int cg = tid >> 6;   // 4 col groups of 16
  float acc[16];
#pragma unroll
  for (int i = 0; i < 16; ++i) acc[i] = bs[cg * 16 + i];
  const float4* Ws4 = (const float4*)Ws;
#pragma unroll 8
  for (int k = 0; k < 64; ++k) {
    float x = xs[r * 65 + k];                    // conflict-free (pad 65)
    float4 w0 = Ws4[k * 16 + cg * 4 + 0];        // wave-uniform broadcast
    float4 w1 = Ws4[k * 16 + cg * 4 + 1];
    float4 w2 = Ws4[k * 16 + cg * 4 + 2];
    float4 w3 = Ws4[k * 16 + cg * 4 + 3];
    acc[0]  += x * w0.x; acc[1]  += x * w0.y; acc[2]  += x * w0.z; acc[3]  += x * w0.w;
    acc[4]  += x * w1.x; acc[5]  += x * w1.y; acc[6]  += x * w1.z; acc[7]  += x * w1.w;
    acc[8]  += x * w2.x; acc[9]  += x * w2.y; acc[10] += x * w2.z; acc[11] += x * w2.w;
    acc[12] += x * w3.x; acc[13] += x * w3.y; acc[14] += x * w3.z; acc[15] += x * w3.w;
  }
  float4* o4 = (float4*)(out + (rowbase + r) * 64 + cg * 16);
#pragma unroll
  for (int q = 0; q < 4; ++q) {
    float4 s;
    s.x = fmaxf(acc[q * 4 + 0], 0.f);
    s.y = fmaxf(acc[q * 4 + 1], 0.f);
    s.z = fmaxf(acc[q * 4 + 2], 0.f);
    s.w = fmaxf(acc[q * 4 + 3], 0.f);
    o4[q] = s;
  }
}

// Fused: S = h_tile . h^T (8 rows x 2048), exact per-row top-50 (radix select,
// lowest-index tie-break like jax.lax.top_k), then either
//   FINAL: write dense masked S rows to out, or
//   MP   : agg = sum_sel v*msg[m];  h2 = relu([h,agg] @ wu + bu).
template <bool FINAL>
__global__ __launch_bounds__(256) void mp_kernel(
    const float* __restrict__ h, const float* __restrict__ msg,
    const float* __restrict__ wu, const float* __restrict__ bu,
    float* __restrict__ outp)
{
  const int tid = threadIdx.x;
  const int b = blockIdx.y;
  const int n0 = blockIdx.x * 8;

  __shared__ float hrL[8 * 64];
  __shared__ unsigned hist[256];
  __shared__ int seli[8][56];
  __shared__ float selv[8][56];
  __shared__ int eqlist[8][64];
  __shared__ unsigned gtc[8], eqc[8], Trow[8];
  __shared__ unsigned sBin, sKcur;
  __shared__ float aggb[8 * 64];

  const float* hb = h + (size_t)b * N_NODES * 64;
  // stage the 8 query rows
  hrL[tid]       = hb[(size_t)n0 * 64 + tid];
  hrL[tid + 256] = hb[(size_t)n0 * 64 + 256 + tid];
  __syncthreads();

  // ---- S tile in registers: acc[r][j], column m = j*256 + tid
  float acc[8][8];
#pragma unroll
  for (int r = 0; r < 8; ++r)
#pragma unroll
    for (int j = 0; j < 8; ++j) acc[r][j] = 0.f;

  const float4* hb4 = (const float4*)hb;
  const float4* hr4 = (const float4*)hrL;
#pragma unroll
  for (int k4 = 0; k4 < 16; ++k4) {
    float4 a[8];
#pragma unroll
    for (int r = 0; r < 8; ++r) a[r] = hr4[r * 16 + k4];  // broadcast ds_read_b128
#pragma unroll
    for (int j = 0; j < 8; ++j) {
      float4 v = hb4[(size_t)(j * 256 + tid) * 16 + k4];
#pragma unroll
      for (int r = 0; r < 8; ++r)
        acc[r][j] += a[r].x * v.x + a[r].y * v.y + a[r].z * v.z + a[r].w * v.w;
    }
  }

  // ---- exact top-50 per row: radix select over ordered-uint, 4 x 8-bit levels
#pragma unroll
  for (int r = 0; r < 8; ++r) {
    unsigned u[8];
#pragma unroll
    for (int j = 0; j < 8; ++j) u[j] = ford(acc[r][j]);
    if (tid == 0) { sKcur = KSEL; gtc[r] = 0; eqc[r] = 0; }
    unsigned pfx = 0;
    for (int lvl = 0; lvl < 4; ++lvl) {
      hist[tid] = 0;
      __syncthreads();
      const int hshift = 24 - 8 * lvl;
#pragma unroll
      for (int j = 0; j < 8; ++j) {
        bool cand = (lvl == 0) || ((u[j] >> (hshift + 8)) == pfx);
        if (cand) atomicAdd(&hist[(u[j] >> hshift) & 255u], 1u);
      }
      __syncthreads();
      if (tid < 64) {  // wave 0: suffix-scan 256 bins, pick threshold bin
        unsigned c0 = hist[tid * 4 + 0], c1 = hist[tid * 4 + 1];
        unsigned c2 = hist[tid * 4 + 2], c3 = hist[tid * 4 + 3];
        unsigned lsum = c0 + c1 + c2 + c3;
        unsigned suff = lsum;
#pragma unroll
        for (int off = 1; off < 64; off <<= 1) {
          unsigned o = __shfl_down(suff, off, 64);
          suff += (tid + off < 64) ? o : 0u;
        }
        unsigned above = suff - lsum;          // count in bins > my top bin
        unsigned Kc = sKcur;                   // lockstep read before any write
        unsigned A3 = above;
        unsigned A2 = A3 + c3;
        unsigned A1 = A2 + c2;
        unsigned A0 = A1 + c1;
        if (A3 < Kc && Kc <= A3 + c3) { sBin = tid * 4 + 3; sKcur = Kc - A3; }
        if (A2 < Kc && Kc <= A2 + c2) { sBin = tid * 4 + 2; sKcur = Kc - A2; }
        if (A1 < Kc && Kc <= A1 + c1) { sBin = tid * 4 + 1; sKcur = Kc - A1; }
        if (A0 < Kc && Kc <= A0 + c0) { sBin = tid * 4 + 0; sKcur = Kc - A0; }
      }
      __syncthreads();
      pfx = (pfx << 8) | sBin;
    }
    const unsigned T = pfx;  // exact 32-bit ordered threshold = K-th largest
    if (tid == 0) Trow[r] = T;
#pragma unroll
    for (int j = 0; j < 8; ++j) {
      int m = j * 256 + tid;
      if (u[j] > T) {
        unsigned p = atomicAdd(&gtc[r], 1u);
        seli[r][p] = m; selv[r][p] = acc[r][j];
      } else if (u[j] == T) {
        unsigned p = atomicAdd(&eqc[r], 1u);
        if (p < 64) eqlist[r][p] = m;          // ties: capped; >need only matters
      }                                        // for exact-equal values (same v)
    }
    __syncthreads();
  }

  // ---- resolve ties: take the `need` smallest indices among equals (jax order)
  if (tid < 8) {
    const int r = tid;
    const int g = (int)gtc[r];
    const int need = KSEL - g;                 // >=1 by construction
    const int e = (eqc[r] < 64u) ? (int)eqc[r] : 64;
    const float Tf = funord(Trow[r]);
    for (int t = 0; t < need; ++t) {
      int bestp = -1, bestm = 0x7FFFFFFF;
      for (int i = 0; i < e; ++i) {
        int mm = eqlist[r][i];
        if (mm < bestm) { bestm = mm; bestp = i; }
      }
      if (bestp < 0) break;
      eqlist[r][bestp] = 0x7FFFFFFF;
      seli[r][g + t] = bestm;
      selv[r][g + t] = Tf;
    }
  }
  __syncthreads();

  if constexpr (FINAL) {
    // dense masked adjacency rows, coalesced stores
    float* ob = outp + ((size_t)b * N_NODES + n0) * N_NODES;
#pragma unroll
    for (int r = 0; r < 8; ++r) {
      const unsigned T = Trow[r];
      const int g = (int)gtc[r];
      const int need = KSEL - g;
#pragma unroll
      for (int j = 0; j < 8; ++j) {
        int m = j * 256 + tid;
        float v = acc[r][j];
        unsigned uu = ford(v);
        bool keep = uu > T;
        if (uu == T) {
          for (int i = 0; i < need; ++i)
            if (seli[r][g + i] == m) { keep = true; break; }
        }
        ob[(size_t)r * N_NODES + m] = keep ? v : 0.f;
      }
    }
  } else {
    // sparse aggregation: agg[r][:] = sum_i v_i * msg[m_i][:]
    const int r = tid >> 5;
    const int lane = tid & 31;
    const float* msgb = msg + (size_t)b * N_NODES * 64;
    float a0 = 0.f, a1 = 0.f;
    for (int i = 0; i < KSEL; ++i) {
      int mi = seli[r][i];                     // broadcast LDS read
      float vv = selv[r][i];
      const float* mr = msgb + (size_t)mi * 64;
      a0 += vv * mr[lane];                     // coalesced 128B per group
      a1 += vv * mr[lane + 32];
    }
    aggb[r * 64 + lane] = a0;
    aggb[r * 64 + lane + 32] = a1;
    __syncthreads();
    // update MLP: h2 = relu([h, agg] @ wu + bu)
    float s0 = bu[lane], s1 = bu[lane + 32];
#pragma unroll 8
    for (int jj = 0; jj < 64; ++jj) {
      float hv = hrL[r * 64 + jj];
      s0 += hv * wu[jj * 64 + lane];
      s1 += hv * wu[jj * 64 + lane + 32];
    }
#pragma unroll 8
    for (int jj = 0; jj < 64; ++jj) {
      float av = aggb[r * 64 + jj];
      s0 += av * wu[(64 + jj) * 64 + lane];
      s1 += av * wu[(64 + jj) * 64 + lane + 32];
    }
    float* o = outp + ((size_t)b * N_NODES + n0 + r) * 64;
    o[lane] = fmaxf(s0, 0.f);
    o[lane + 32] = fmaxf(s1, 0.f);
  }
}

extern "C" void kernel_launch(void* const* d_in, const int* in_sizes, int n_in,
                              void* d_out, int out_size, void* d_ws, size_t ws_size,
                              hipStream_t stream)
{
  (void)in_sizes; (void)n_in; (void)out_size; (void)ws_size;
  const float* x   = (const float*)d_in[0];
  const float* ew0 = (const float*)d_in[1];
  const float* eb0 = (const float*)d_in[2];
  const float* ew1 = (const float*)d_in[3];
  const float* eb1 = (const float*)d_in[4];
  const float* w0m = (const float*)d_in[5];
  const float* b0m = (const float*)d_in[6];
  const float* w0u = (const float*)d_in[7];
  const float* b0u = (const float*)d_in[8];
  const float* w1m = (const float*)d_in[9];
  const float* b1m = (const float*)d_in[10];
  const float* w1u = (const float*)d_in[11];
  const float* b1u = (const float*)d_in[12];
  float* out = (float*)d_out;
  float* ws = (float*)d_ws;

  const size_t BUF = (size_t)8 * N_NODES * 64;  // 1,048,576 floats = 4 MB
  float* A  = ws;            // h buffers (12 MB total workspace used)
  float* Bf = ws + BUF;
  float* C  = ws + 2 * BUF;

  // embedding MLP (2 layers)
  linrelu_kernel<<<256, 256, 0, stream>>>(x, ew0, eb0, C);
  linrelu_kernel<<<256, 256, 0, stream>>>(C, ew1, eb1, A);

  // MP layer 0
  linrelu_kernel<<<256, 256, 0, stream>>>(A, w0m, b0m, C);
  mp_kernel<false><<<dim3(256, 8), 256, 0, stream>>>(A, C, w0u, b0u, Bf);

  // MP layer 1
  linrelu_kernel<<<256, 256, 0, stream>>>(Bf, w1m, b1m, C);
  mp_kernel<false><<<dim3(256, 8), 256, 0, stream>>>(Bf, C, w1u, b1u, A);

  // final dense top-k adjacency
  mp_kernel<true><<<dim3(256, 8), 256, 0, stream>>>(A, nullptr, nullptr, nullptr, out);
}

// Round 2
// 888.719 us; speedup vs baseline: 7.3532x; 7.3532x over previous
//
#include <hip/hip_runtime.h>

#define N_NODES 2048
#define KSEL 50

// ---- order-preserving fp32 <-> uint map (monotone: bigger float => bigger uint)
__device__ __forceinline__ unsigned ford(float f) {
  unsigned b = __float_as_uint(f);
  return b ^ ((b & 0x80000000u) ? 0xFFFFFFFFu : 0x80000000u);
}
__device__ __forceinline__ float funord(unsigned u) {
  unsigned b = (u & 0x80000000u) ? (u ^ 0x80000000u) : ~u;
  return __uint_as_float(b);
}

// out[row][c] = relu(bias[c] + sum_k in[row][k] * W[k][c]); 64 rows/block, 256 thr.
// WRITE_T: also emit outT[batch][c][n] (feature-major) for coalesced column reads
// in mp_kernel.
template <bool WRITE_T>
__global__ __launch_bounds__(256) void linrelu_kernel(
    const float* __restrict__ in, const float* __restrict__ W,
    const float* __restrict__ bias, float* __restrict__ out,
    float* __restrict__ outT)
{
  const int tid = threadIdx.x;
  const size_t rowbase = (size_t)blockIdx.x * 64;
  __shared__ float xs[64 * 65];   // reused as transpose buffer after compute
  __shared__ float Ws[64 * 64];
  __shared__ float bs[64];
#pragma unroll
  for (int i = 0; i < 16; ++i) {
    int idx = tid + 256 * i;
    xs[(idx >> 6) * 65 + (idx & 63)] = in[rowbase * 64 + idx];
    Ws[idx] = W[idx];
  }
  if (tid < 64) bs[tid] = bias[tid];
  __syncthreads();
  const int r = tid & 63;    // lane-per-row
  const int cg = tid >> 6;   // 4 col groups of 16
  float acc[16];
#pragma unroll
  for (int i = 0; i < 16; ++i) acc[i] = bs[cg * 16 + i];
  const float4* Ws4 = (const float4*)Ws;
#pragma unroll 8
  for (int k = 0; k < 64; ++k) {
    float x = xs[r * 65 + k];                    // conflict-free (pad 65)
    float4 w0 = Ws4[k * 16 + cg * 4 + 0];        // wave-uniform broadcast
    float4 w1 = Ws4[k * 16 + cg * 4 + 1];
    float4 w2 = Ws4[k * 16 + cg * 4 + 2];
    float4 w3 = Ws4[k * 16 + cg * 4 + 3];
    acc[0]  += x * w0.x; acc[1]  += x * w0.y; acc[2]  += x * w0.z; acc[3]  += x * w0.w;
    acc[4]  += x * w1.x; acc[5]  += x * w1.y; acc[6]  += x * w1.z; acc[7]  += x * w1.w;
    acc[8]  += x * w2.x; acc[9]  += x * w2.y; acc[10] += x * w2.z; acc[11] += x * w2.w;
    acc[12] += x * w3.x; acc[13] += x * w3.y; acc[14] += x * w3.z; acc[15] += x * w3.w;
  }
#pragma unroll
  for (int i = 0; i < 16; ++i) acc[i] = fmaxf(acc[i], 0.f);
  float4* o4 = (float4*)(out + (rowbase + r) * 64 + cg * 16);
#pragma unroll
  for (int q = 0; q < 4; ++q)
    o4[q] = make_float4(acc[q * 4 + 0], acc[q * 4 + 1], acc[q * 4 + 2], acc[q * 4 + 3]);

  if constexpr (WRITE_T) {
    __syncthreads();                 // xs reads done; reuse xs as [c][row] buffer
#pragma unroll
    for (int i = 0; i < 16; ++i)
      xs[(cg * 16 + i) * 65 + r] = acc[i];       // bank (c+r)%32: 2-way, free
    __syncthreads();
    const size_t bb = rowbase >> 11;             // batch (2048 rows per batch)
    const int nbase = (int)(rowbase & 2047);
    const int c = tid >> 2, seg = tid & 3;       // 64 feats x 4 segments of 16
    float* oT = outT + bb * 64 * N_NODES + (size_t)c * N_NODES + nbase + seg * 16;
#pragma unroll
    for (int q = 0; q < 4; ++q) {
      float4 v = make_float4(xs[c * 65 + seg * 16 + q * 4 + 0],
                             xs[c * 65 + seg * 16 + q * 4 + 1],
                             xs[c * 65 + seg * 16 + q * 4 + 2],
                             xs[c * 65 + seg * 16 + q * 4 + 3]);
      ((float4*)oT)[q] = v;
    }
  }
}

// Fused: S = h_tile . h^T (8 rows x 2048) with COALESCED column reads from hT,
// exact per-row top-50 (batched radix select), then either
//   FINAL: write dense masked S rows, or
//   MP   : agg = sum_sel v*msg[m];  h2 = relu([h,agg] @ wu + bu); also h2T.
template <bool FINAL>
__global__ __launch_bounds__(256, 2) void mp_kernel(
    const float* __restrict__ h, const float* __restrict__ hT,
    const float* __restrict__ msg,
    const float* __restrict__ wu, const float* __restrict__ bu,
    float* __restrict__ outp, float* __restrict__ outT)
{
  const int tid = threadIdx.x;
  const int bid = blockIdx.x;
  const int b = bid & 7;                  // round-robin blockIdx->XCD: 1 batch/XCD
  const int n0 = (bid >> 3) * 8;

  __shared__ float hrL[8 * 64];
  __shared__ unsigned hist[8][256];       // batched radix histograms (8 KB)
  __shared__ unsigned pfxs[8], Kcur[8], binsel[8];
  __shared__ unsigned gtc[8], eqc[8];
  __shared__ int seli[8][64];
  __shared__ float selv[8][64];
  __shared__ int eqlist[8][64];
  __shared__ float aggb[8 * 64];
  __shared__ float ot[64 * 9];            // h2T staging (MP only)

  const float* hb  = h  + (size_t)b * N_NODES * 64;
  const float* hTb = hT + (size_t)b * 64 * N_NODES;
  hrL[tid]       = hb[(size_t)n0 * 64 + tid];
  hrL[tid + 256] = hb[(size_t)n0 * 64 + 256 + tid];
  if (tid < 8) { Kcur[tid] = KSEL; gtc[tid] = 0; eqc[tid] = 0; pfxs[tid] = 0; }
  __syncthreads();

  // ---- S tile in registers: acc[r*8 + p*2 + e], column m = p*512 + 2*tid + e
  float acc[64];
#pragma unroll
  for (int i = 0; i < 64; ++i) acc[i] = 0.f;

  const float4* hr4 = (const float4*)hrL;
#pragma unroll 2
  for (int k4 = 0; k4 < 16; ++k4) {
    float4 a[8];
#pragma unroll
    for (int r = 0; r < 8; ++r) a[r] = hr4[r * 16 + k4];  // broadcast (uniform)
#pragma unroll
    for (int kk = 0; kk < 4; ++kk) {
      const int k = k4 * 4 + kk;
      const float2* rowp = (const float2*)(hTb + (size_t)k * N_NODES) + tid;
      float2 v[4];
#pragma unroll
      for (int p = 0; p < 4; ++p) v[p] = rowp[p * 256];   // coalesced 8B/lane
#pragma unroll
      for (int r = 0; r < 8; ++r) {
        const float ar = ((const float*)&a[r])[kk];
#pragma unroll
        for (int p = 0; p < 4; ++p) {
          acc[r * 8 + p * 2 + 0] += ar * v[p].x;
          acc[r * 8 + p * 2 + 1] += ar * v[p].y;
        }
      }
    }
  }

  // ---- in-place convert to order-preserving uints (values recovered by funord)
  unsigned uacc[64];
#pragma unroll
  for (int i = 0; i < 64; ++i) uacc[i] = ford(acc[i]);

  // ---- batched exact top-50: radix select, all 8 rows per pass, 4x8-bit levels
  unsigned* hf = &hist[0][0];
  for (int lvl = 0; lvl < 4; ++lvl) {
#pragma unroll
    for (int i = 0; i < 8; ++i) hf[tid + 256 * i] = 0;
    __syncthreads();
    const int shift = 24 - 8 * lvl;
#pragma unroll
    for (int r = 0; r < 8; ++r) {
      const unsigned pr = pfxs[r];
#pragma unroll
      for (int j = 0; j < 8; ++j) {
        unsigned u = uacc[r * 8 + j];
        bool cand = (lvl == 0) || ((u >> (shift + 8)) == pr);
        if (cand) atomicAdd(&hist[r][(u >> shift) & 255u], 1u);
      }
    }
    __syncthreads();
    {   // wave w scans rows 2w, 2w+1
      const int w = tid >> 6, lane = tid & 63;
#pragma unroll
      for (int q = 0; q < 2; ++q) {
        const int rr = w * 2 + q;
        unsigned c0 = hist[rr][lane * 4 + 0], c1 = hist[rr][lane * 4 + 1];
        unsigned c2 = hist[rr][lane * 4 + 2], c3 = hist[rr][lane * 4 + 3];
        unsigned lsum = c0 + c1 + c2 + c3;
        unsigned suff = lsum;
#pragma unroll
        for (int off = 1; off < 64; off <<= 1) {
          unsigned o = __shfl_down(suff, off, 64);
          suff += (lane + off < 64) ? o : 0u;
        }
        unsigned Kc = Kcur[rr];                // all lanes read before any write
        unsigned A3 = suff - lsum;
        unsigned A2 = A3 + c3;
        unsigned A1 = A2 + c2;
        unsigned A0 = A1 + c1;
        if (A3 < Kc && Kc <= A3 + c3) { binsel[rr] = lane * 4 + 3; Kcur[rr] = Kc - A3; }
        if (A2 < Kc && Kc <= A2 + c2) { binsel[rr] = lane * 4 + 2; Kcur[rr] = Kc - A2; }
        if (A1 < Kc && Kc <= A1 + c1) { binsel[rr] = lane * 4 + 1; Kcur[rr] = Kc - A1; }
        if (A0 < Kc && Kc <= A0 + c0) { binsel[rr] = lane * 4 + 0; Kcur[rr] = Kc - A0; }
      }
    }
    __syncthreads();
    if (tid < 8) pfxs[tid] = (pfxs[tid] << 8) | binsel[tid];
    __syncthreads();
  }

  // ---- extract winners (> T) and tie candidates (== T)
#pragma unroll
  for (int r = 0; r < 8; ++r) {
    const unsigned T = pfxs[r];
#pragma unroll
    for (int j = 0; j < 8; ++j) {
      const int p = j >> 1, e = j & 1;
      const int m = p * 512 + 2 * tid + e;
      const unsigned u = uacc[r * 8 + j];
      if (u > T) {
        unsigned pos = atomicAdd(&gtc[r], 1u);
        seli[r][pos] = m; selv[r][pos] = funord(u);
      } else if (u == T) {
        unsigned pos = atomicAdd(&eqc[r], 1u);
        if (pos < 64) eqlist[r][pos] = m;
      }
    }
  }
  __syncthreads();

  // ---- resolve ties: `need` smallest indices among equals (jax order)
  if (tid < 8) {
    const int r = tid;
    const int g = (int)gtc[r];
    const int need = KSEL - g;
    const int e = (eqc[r] < 64u) ? (int)eqc[r] : 64;
    const float Tf = funord(pfxs[r]);
    for (int t = 0; t < need; ++t) {
      int bestp = -1, bestm = 0x7FFFFFFF;
      for (int i = 0; i < e; ++i) {
        int mm = eqlist[r][i];
        if (mm < bestm) { bestm = mm; bestp = i; }
      }
      if (bestp < 0) break;
      eqlist[r][bestp] = 0x7FFFFFFF;
      seli[r][g + t] = bestm;
      selv[r][g + t] = Tf;
    }
  }
  __syncthreads();

  if constexpr (FINAL) {
    float* ob = outp + ((size_t)b * N_NODES + n0) * N_NODES;
#pragma unroll
    for (int r = 0; r < 8; ++r) {
      const unsigned T = pfxs[r];
      const int g = (int)gtc[r];
      const int need = KSEL - g;
#pragma unroll
      for (int p = 0; p < 4; ++p) {
        float2 w;
#pragma unroll
        for (int e = 0; e < 2; ++e) {
          const unsigned u = uacc[r * 8 + p * 2 + e];
          const int m = p * 512 + 2 * tid + e;
          bool keep = u > T;
          if (u == T) {
            for (int i = 0; i < need; ++i)
              if (seli[r][g + i] == m) { keep = true; break; }
          }
          ((float*)&w)[e] = keep ? funord(u) : 0.f;
        }
        *(float2*)(ob + (size_t)r * N_NODES + p * 512 + 2 * tid) = w;
      }
    }
  } else {
    // sparse aggregation: agg[r][:] = sum_i v_i * msg[m_i][:]
    const int r = tid >> 5;
    const int lane = tid & 31;
    const float* msgb = msg + (size_t)b * N_NODES * 64;
    float a0 = 0.f, a1 = 0.f;
    for (int i = 0; i < KSEL; ++i) {
      int mi = seli[r][i];
      float vv = selv[r][i];
      const float* mr = msgb + (size_t)mi * 64;
      a0 += vv * mr[lane];
      a1 += vv * mr[lane + 32];
    }
    aggb[r * 64 + lane] = a0;
    aggb[r * 64 + lane + 32] = a1;
    __syncthreads();
    float s0 = bu[lane], s1 = bu[lane + 32];
#pragma unroll 8
    for (int jj = 0; jj < 64; ++jj) {
      float hv = hrL[r * 64 + jj];
      s0 += hv * wu[jj * 64 + lane];
      s1 += hv * wu[jj * 64 + lane + 32];
    }
#pragma unroll 8
    for (int jj = 0; jj < 64; ++jj) {
      float av = aggb[r * 64 + jj];
      s0 += av * wu[(64 + jj) * 64 + lane];
      s1 += av * wu[(64 + jj) * 64 + lane + 32];
    }
    s0 = fmaxf(s0, 0.f); s1 = fmaxf(s1, 0.f);
    float* o = outp + ((size_t)b * N_NODES + n0 + r) * 64;
    o[lane] = s0;
    o[lane + 32] = s1;
    ot[lane * 9 + r] = s0;                 // bank (9f+r)%32: conflict-free
    ot[(lane + 32) * 9 + r] = s1;
    __syncthreads();
    for (int i = tid; i < 512; i += 256) { // flush h2T (32B segments)
      int f = i >> 3, rr = i & 7;
      outT[(size_t)b * 64 * N_NODES + (size_t)f * N_NODES + n0 + rr] = ot[f * 9 + rr];
    }
  }
}

extern "C" void kernel_launch(void* const* d_in, const int* in_sizes, int n_in,
                              void* d_out, int out_size, void* d_ws, size_t ws_size,
                              hipStream_t stream)
{
  (void)in_sizes; (void)n_in; (void)out_size; (void)ws_size;
  const float* x   = (const float*)d_in[0];
  const float* ew0 = (const float*)d_in[1];
  const float* eb0 = (const float*)d_in[2];
  const float* ew1 = (const float*)d_in[3];
  const float* eb1 = (const float*)d_in[4];
  const float* w0m = (const float*)d_in[5];
  const float* b0m = (const float*)d_in[6];
  const float* w0u = (const float*)d_in[7];
  const float* b0u = (const float*)d_in[8];
  const float* w1m = (const float*)d_in[9];
  const float* b1m = (const float*)d_in[10];
  const float* w1u = (const float*)d_in[11];
  const float* b1u = (const float*)d_in[12];
  float* out = (float*)d_out;
  float* ws = (float*)d_ws;

  const size_t BUF = (size_t)8 * N_NODES * 64;  // 4 MB each
  float* A   = ws;
  float* AT  = ws + 1 * BUF;
  float* Bf  = ws + 2 * BUF;
  float* BfT = ws + 3 * BUF;
  float* C   = ws + 4 * BUF;                    // 20 MB total workspace

  // embedding MLP
  linrelu_kernel<false><<<256, 256, 0, stream>>>(x, ew0, eb0, C, nullptr);
  linrelu_kernel<true ><<<256, 256, 0, stream>>>(C, ew1, eb1, A, AT);

  // MP layer 0
  linrelu_kernel<false><<<256, 256, 0, stream>>>(A, w0m, b0m, C, nullptr);
  mp_kernel<false><<<2048, 256, 0, stream>>>(A, AT, C, w0u, b0u, Bf, BfT);

  // MP layer 1
  linrelu_kernel<false><<<256, 256, 0, stream>>>(Bf, w1m, b1m, C, nullptr);
  mp_kernel<false><<<2048, 256, 0, stream>>>(Bf, BfT, C, w1u, b1u, A, AT);

  // final dense top-k adjacency
  mp_kernel<true><<<2048, 256, 0, stream>>>(A, AT, nullptr, nullptr, nullptr, out, nullptr);
}

// Round 3
// 747.683 us; speedup vs baseline: 8.7403x; 1.1886x over previous
//
#include <hip/hip_runtime.h>

#define N_NODES 2048
#define KSEL 50

// ---- order-preserving fp32 <-> uint map (monotone: bigger float => bigger uint)
__device__ __forceinline__ unsigned ford(float f) {
  unsigned b = __float_as_uint(f);
  return b ^ ((b & 0x80000000u) ? 0xFFFFFFFFu : 0x80000000u);
}
__device__ __forceinline__ float funord(unsigned u) {
  unsigned b = (u & 0x80000000u) ? (u ^ 0x80000000u) : ~u;
  return __uint_as_float(b);
}

// out[row][c] = relu(bias[c] + sum_k in[row][k] * W[k][c]); 64 rows/block, 256 thr.
// WRITE_T: also emit outT[batch][c][n] (feature-major) for coalesced column reads
// in mp_kernel.
template <bool WRITE_T>
__global__ __launch_bounds__(256) void linrelu_kernel(
    const float* __restrict__ in, const float* __restrict__ W,
    const float* __restrict__ bias, float* __restrict__ out,
    float* __restrict__ outT)
{
  const int tid = threadIdx.x;
  const size_t rowbase = (size_t)blockIdx.x * 64;
  __shared__ float xs[64 * 65];   // reused as transpose buffer after compute
  __shared__ float Ws[64 * 64];
  __shared__ float bs[64];
#pragma unroll
  for (int i = 0; i < 16; ++i) {
    int idx = tid + 256 * i;
    xs[(idx >> 6) * 65 + (idx & 63)] = in[rowbase * 64 + idx];
    Ws[idx] = W[idx];
  }
  if (tid < 64) bs[tid] = bias[tid];
  __syncthreads();
  const int r = tid & 63;    // lane-per-row
  const int cg = tid >> 6;   // 4 col groups of 16
  float acc[16];
#pragma unroll
  for (int i = 0; i < 16; ++i) acc[i] = bs[cg * 16 + i];
  const float4* Ws4 = (const float4*)Ws;
#pragma unroll 8
  for (int k = 0; k < 64; ++k) {
    float x = xs[r * 65 + k];                    // conflict-free (pad 65)
    float4 w0 = Ws4[k * 16 + cg * 4 + 0];        // wave-uniform broadcast
    float4 w1 = Ws4[k * 16 + cg * 4 + 1];
    float4 w2 = Ws4[k * 16 + cg * 4 + 2];
    float4 w3 = Ws4[k * 16 + cg * 4 + 3];
    acc[0]  += x * w0.x; acc[1]  += x * w0.y; acc[2]  += x * w0.z; acc[3]  += x * w0.w;
    acc[4]  += x * w1.x; acc[5]  += x * w1.y; acc[6]  += x * w1.z; acc[7]  += x * w1.w;
    acc[8]  += x * w2.x; acc[9]  += x * w2.y; acc[10] += x * w2.z; acc[11] += x * w2.w;
    acc[12] += x * w3.x; acc[13] += x * w3.y; acc[14] += x * w3.z; acc[15] += x * w3.w;
  }
#pragma unroll
  for (int i = 0; i < 16; ++i) acc[i] = fmaxf(acc[i], 0.f);
  float4* o4 = (float4*)(out + (rowbase + r) * 64 + cg * 16);
#pragma unroll
  for (int q = 0; q < 4; ++q)
    o4[q] = make_float4(acc[q * 4 + 0], acc[q * 4 + 1], acc[q * 4 + 2], acc[q * 4 + 3]);

  if constexpr (WRITE_T) {
    __syncthreads();                 // xs reads done; reuse xs as [c][row] buffer
#pragma unroll
    for (int i = 0; i < 16; ++i)
      xs[(cg * 16 + i) * 65 + r] = acc[i];       // bank (c+r)%32: 2-way, free
    __syncthreads();
    const size_t bb = rowbase >> 11;             // batch (2048 rows per batch)
    const int nbase = (int)(rowbase & 2047);
    const int c = tid >> 2, seg = tid & 3;       // 64 feats x 4 segments of 16
    float* oT = outT + bb * 64 * N_NODES + (size_t)c * N_NODES + nbase + seg * 16;
#pragma unroll
    for (int q = 0; q < 4; ++q) {
      float4 v = make_float4(xs[c * 65 + seg * 16 + q * 4 + 0],
                             xs[c * 65 + seg * 16 + q * 4 + 1],
                             xs[c * 65 + seg * 16 + q * 4 + 2],
                             xs[c * 65 + seg * 16 + q * 4 + 3]);
      ((float4*)oT)[q] = v;
    }
  }
}

// Fused: S = h_tile . h^T (8 rows x 2048), coalesced + software-pipelined column
// stream from hT, exact per-row top-50 (batched radix select, 2 barriers/level,
// bank-padded histograms), then either
//   FINAL: write dense masked S rows, or
//   MP   : agg = sum_sel v*msg[m];  h2 = relu([h,agg] @ wu + bu); also h2T.
template <bool FINAL>
__global__ __launch_bounds__(256, 4) void mp_kernel(
    const float* __restrict__ h, const float* __restrict__ hT,
    const float* __restrict__ msg,
    const float* __restrict__ wu, const float* __restrict__ bu,
    float* __restrict__ outp, float* __restrict__ outT)
{
  const int tid = threadIdx.x;
  const int bid = blockIdx.x;
  const int b = bid & 7;                  // round-robin blockIdx->XCD: 1 batch/XCD
  const int n0 = (bid >> 3) * 8;

  __shared__ float hrL[8 * 64];
  __shared__ unsigned hist[8][257];       // +1 pad: row r hot bins start at bank r
  __shared__ unsigned pfxs[8], Kcur[8];
  __shared__ unsigned gtc[8], eqc[8];
  __shared__ int seli[8][64];
  __shared__ float selv[8][64];
  __shared__ int eqlist[8][64];
  __shared__ float aggb[8 * 64];
  __shared__ float ot[64 * 9];            // h2T staging (MP only)

  const float* hb  = h  + (size_t)b * N_NODES * 64;
  const float* hTb = hT + (size_t)b * 64 * N_NODES;
  const float* colp = hTb + 2 * tid;      // lane base for column stream

  // issue first column loads before any LDS dependency (overlap with staging)
  float2 cur[4], nxt[4];
#pragma unroll
  for (int p = 0; p < 4; ++p) cur[p] = *(const float2*)(colp + p * 512);

  hrL[tid]       = hb[(size_t)n0 * 64 + tid];
  hrL[tid + 256] = hb[(size_t)n0 * 64 + 256 + tid];
  if (tid < 8) { Kcur[tid] = KSEL; gtc[tid] = 0; eqc[tid] = 0; pfxs[tid] = 0; }
  for (int i = tid; i < 8 * 257; i += 256) (&hist[0][0])[i] = 0;
  __syncthreads();

  // ---- S tile in registers: acc[r*8 + p*2 + e], column m = p*512 + 2*tid + e
  float acc[64];
#pragma unroll
  for (int i = 0; i < 64; ++i) acc[i] = 0.f;

  const float4* hr4 = (const float4*)hrL;
#pragma unroll
  for (int k4 = 0; k4 < 16; ++k4) {
    float4 a[8];
#pragma unroll
    for (int r = 0; r < 8; ++r) a[r] = hr4[r * 16 + k4];  // broadcast (uniform)
#pragma unroll
    for (int kk = 0; kk < 4; ++kk) {
      const int k = k4 * 4 + kk;
      if (k < 63) {                                        // prefetch k+1
#pragma unroll
        for (int p = 0; p < 4; ++p)
          nxt[p] = *(const float2*)(colp + (size_t)(k + 1) * N_NODES + p * 512);
      }
#pragma unroll
      for (int r = 0; r < 8; ++r) {
        const float ar = ((const float*)&a[r])[kk];
#pragma unroll
        for (int p = 0; p < 4; ++p) {
          acc[r * 8 + p * 2 + 0] += ar * cur[p].x;
          acc[r * 8 + p * 2 + 1] += ar * cur[p].y;
        }
      }
#pragma unroll
      for (int p = 0; p < 4; ++p) cur[p] = nxt[p];
    }
  }

  // ---- in-place convert to order-preserving uints (values recovered by funord)
  unsigned uacc[64];
#pragma unroll
  for (int i = 0; i < 64; ++i) uacc[i] = ford(acc[i]);

  // ---- batched exact top-50: radix select, 8 rows/pass, 4x8-bit, 2 barriers/lvl
  for (int lvl = 0; lvl < 4; ++lvl) {
    const int shift = 24 - 8 * lvl;
#pragma unroll
    for (int r = 0; r < 8; ++r) {
      const unsigned pr = pfxs[r];
#pragma unroll
      for (int j = 0; j < 8; ++j) {
        unsigned u = uacc[r * 8 + j];
        bool cand = (lvl == 0) || ((u >> (shift + 8)) == pr);
        if (cand) atomicAdd(&hist[r][(u >> shift) & 255u], 1u);
      }
    }
    __syncthreads();
    {   // wave w scans rows 2w,2w+1; re-zeros its bins; picks threshold bin
      const int w = tid >> 6, lane = tid & 63;
#pragma unroll
      for (int q = 0; q < 2; ++q) {
        const int rr = w * 2 + q;
        unsigned c0 = hist[rr][lane * 4 + 0], c1 = hist[rr][lane * 4 + 1];
        unsigned c2 = hist[rr][lane * 4 + 2], c3 = hist[rr][lane * 4 + 3];
        hist[rr][lane * 4 + 0] = 0; hist[rr][lane * 4 + 1] = 0;
        hist[rr][lane * 4 + 2] = 0; hist[rr][lane * 4 + 3] = 0;
        unsigned lsum = c0 + c1 + c2 + c3;
        unsigned suff = lsum;
#pragma unroll
        for (int off = 1; off < 64; off <<= 1) {
          unsigned o = __shfl_down(suff, off, 64);
          suff += (lane + off < 64) ? o : 0u;
        }
        unsigned Kc = Kcur[rr];                // lockstep read before any write
        unsigned A3 = suff - lsum;
        unsigned A2 = A3 + c3;
        unsigned A1 = A2 + c2;
        unsigned A0 = A1 + c1;
        // exactly one (lane, sub-bin) interval contains rank Kc
        if (A3 < Kc && Kc <= A3 + c3) { Kcur[rr] = Kc - A3; pfxs[rr] = (pfxs[rr] << 8) | (lane * 4 + 3); }
        if (A2 < Kc && Kc <= A2 + c2) { Kcur[rr] = Kc - A2; pfxs[rr] = (pfxs[rr] << 8) | (lane * 4 + 2); }
        if (A1 < Kc && Kc <= A1 + c1) { Kcur[rr] = Kc - A1; pfxs[rr] = (pfxs[rr] << 8) | (lane * 4 + 1); }
        if (A0 < Kc && Kc <= A0 + c0) { Kcur[rr] = Kc - A0; pfxs[rr] = (pfxs[rr] << 8) | (lane * 4 + 0); }
      }
    }
    __syncthreads();
  }

  // ---- extract winners (> T) and tie candidates (== T)
#pragma unroll
  for (int r = 0; r < 8; ++r) {
    const unsigned T = pfxs[r];
#pragma unroll
    for (int j = 0; j < 8; ++j) {
      const int p = j >> 1, e = j & 1;
      const int m = p * 512 + 2 * tid + e;
      const unsigned u = uacc[r * 8 + j];
      if (u > T) {
        unsigned pos = atomicAdd(&gtc[r], 1u);
        seli[r][pos] = m; selv[r][pos] = funord(u);
      } else if (u == T) {
        unsigned pos = atomicAdd(&eqc[r], 1u);
        if (pos < 64) eqlist[r][pos] = m;
      }
    }
  }
  __syncthreads();

  // ---- resolve ties: `need` smallest indices among equals (jax order)
  if (tid < 8) {
    const int r = tid;
    const int g = (int)gtc[r];
    const int need = KSEL - g;
    const int e = (eqc[r] < 64u) ? (int)eqc[r] : 64;
    const float Tf = funord(pfxs[r]);
    for (int t = 0; t < need; ++t) {
      int bestp = -1, bestm = 0x7FFFFFFF;
      for (int i = 0; i < e; ++i) {
        int mm = eqlist[r][i];
        if (mm < bestm) { bestm = mm; bestp = i; }
      }
      if (bestp < 0) break;
      eqlist[r][bestp] = 0x7FFFFFFF;
      seli[r][g + t] = bestm;
      selv[r][g + t] = Tf;
    }
  }
  __syncthreads();

  if constexpr (FINAL) {
    float* ob = outp + ((size_t)b * N_NODES + n0) * N_NODES;
#pragma unroll
    for (int r = 0; r < 8; ++r) {
      const unsigned T = pfxs[r];
      const int g = (int)gtc[r];
      const int need = KSEL - g;
#pragma unroll
      for (int p = 0; p < 4; ++p) {
        float2 w;
#pragma unroll
        for (int e = 0; e < 2; ++e) {
          const unsigned u = uacc[r * 8 + p * 2 + e];
          const int m = p * 512 + 2 * tid + e;
          bool keep = u > T;
          if (u == T) {
            for (int i = 0; i < need; ++i)
              if (seli[r][g + i] == m) { keep = true; break; }
          }
          ((float*)&w)[e] = keep ? funord(u) : 0.f;
        }
        *(float2*)(ob + (size_t)r * N_NODES + p * 512 + 2 * tid) = w;
      }
    }
  } else {
    // sparse aggregation: agg[r][:] = sum_i v_i * msg[m_i][:]
    const int r = tid >> 5;
    const int lane = tid & 31;
    const float* msgb = msg + (size_t)b * N_NODES * 64;
    float a0 = 0.f, a1 = 0.f;
    for (int i = 0; i < KSEL; ++i) {
      int mi = seli[r][i];
      float vv = selv[r][i];
      const float* mr = msgb + (size_t)mi * 64;
      a0 += vv * mr[lane];
      a1 += vv * mr[lane + 32];
    }
    aggb[r * 64 + lane] = a0;
    aggb[r * 64 + lane + 32] = a1;
    __syncthreads();
    float s0 = bu[lane], s1 = bu[lane + 32];
#pragma unroll 8
    for (int jj = 0; jj < 64; ++jj) {
      float hv = hrL[r * 64 + jj];
      s0 += hv * wu[jj * 64 + lane];
      s1 += hv * wu[jj * 64 + lane + 32];
    }
#pragma unroll 8
    for (int jj = 0; jj < 64; ++jj) {
      float av = aggb[r * 64 + jj];
      s0 += av * wu[(64 + jj) * 64 + lane];
      s1 += av * wu[(64 + jj) * 64 + lane + 32];
    }
    s0 = fmaxf(s0, 0.f); s1 = fmaxf(s1, 0.f);
    float* o = outp + ((size_t)b * N_NODES + n0 + r) * 64;
    o[lane] = s0;
    o[lane + 32] = s1;
    ot[lane * 9 + r] = s0;                 // bank (9f+r)%32: conflict-free
    ot[(lane + 32) * 9 + r] = s1;
    __syncthreads();
    for (int i = tid; i < 512; i += 256) { // flush h2T (32B segments)
      int f = i >> 3, rr = i & 7;
      outT[(size_t)b * 64 * N_NODES + (size_t)f * N_NODES + n0 + rr] = ot[f * 9 + rr];
    }
  }
}

extern "C" void kernel_launch(void* const* d_in, const int* in_sizes, int n_in,
                              void* d_out, int out_size, void* d_ws, size_t ws_size,
                              hipStream_t stream)
{
  (void)in_sizes; (void)n_in; (void)out_size; (void)ws_size;
  const float* x   = (const float*)d_in[0];
  const float* ew0 = (const float*)d_in[1];
  const float* eb0 = (const float*)d_in[2];
  const float* ew1 = (const float*)d_in[3];
  const float* eb1 = (const float*)d_in[4];
  const float* w0m = (const float*)d_in[5];
  const float* b0m = (const float*)d_in[6];
  const float* w0u = (const float*)d_in[7];
  const float* b0u = (const float*)d_in[8];
  const float* w1m = (const float*)d_in[9];
  const float* b1m = (const float*)d_in[10];
  const float* w1u = (const float*)d_in[11];
  const float* b1u = (const float*)d_in[12];
  float* out = (float*)d_out;
  float* ws = (float*)d_ws;

  const size_t BUF = (size_t)8 * N_NODES * 64;  // 4 MB each
  float* A   = ws;
  float* AT  = ws + 1 * BUF;
  float* Bf  = ws + 2 * BUF;
  float* BfT = ws + 3 * BUF;
  float* C   = ws + 4 * BUF;                    // 20 MB total workspace

  // embedding MLP
  linrelu_kernel<false><<<256, 256, 0, stream>>>(x, ew0, eb0, C, nullptr);
  linrelu_kernel<true ><<<256, 256, 0, stream>>>(C, ew1, eb1, A, AT);

  // MP layer 0
  linrelu_kernel<false><<<256, 256, 0, stream>>>(A, w0m, b0m, C, nullptr);
  mp_kernel<false><<<2048, 256, 0, stream>>>(A, AT, C, w0u, b0u, Bf, BfT);

  // MP layer 1
  linrelu_kernel<false><<<256, 256, 0, stream>>>(Bf, w1m, b1m, C, nullptr);
  mp_kernel<false><<<2048, 256, 0, stream>>>(Bf, BfT, C, w1u, b1u, A, AT);

  // final dense top-k adjacency
  mp_kernel<true><<<2048, 256, 0, stream>>>(A, AT, nullptr, nullptr, nullptr, out, nullptr);
}

// Round 4
// 662.733 us; speedup vs baseline: 9.8606x; 1.1282x over previous
//
#include <hip/hip_runtime.h>

#define N_NODES 2048
#define KSEL 50

typedef float v2f __attribute__((ext_vector_type(2)));

// ---- order-preserving fp32 <-> uint map (monotone: bigger float => bigger uint)
__device__ __forceinline__ unsigned ford(float f) {
  unsigned b = __float_as_uint(f);
  return b ^ ((b & 0x80000000u) ? 0xFFFFFFFFu : 0x80000000u);
}
__device__ __forceinline__ float funord(unsigned u) {
  unsigned b = (u & 0x80000000u) ? (u ^ 0x80000000u) : ~u;
  return __uint_as_float(b);
}

// hist storage: bin b, sub-counter s (s = lane&1): word (b&63)*8 + (b>>6)*2 + s.
// Scan: lane reads words [lane*8, lane*8+8) = bins {g*64+lane} x {s} as 2x uint4.
#define HROW 516  // 512 + 4 pad: rows stagger 4 banks, 16B-aligned
__device__ __forceinline__ int hidx(unsigned b, int s) {
  return (int)(((b & 63u) << 3) | ((b >> 6) << 1)) | s;
}

// shared single-layer MLP tile: acc[16] = relu(bias + xs^T W), xs transposed layout
__device__ __forceinline__ void mlp_layer(float acc[16], const float* xs,
                                          const float* Ws, const float* bs,
                                          int r, int cg) {
  const float4* Ws4 = (const float4*)Ws;
#pragma unroll
  for (int i = 0; i < 16; ++i) acc[i] = bs[cg * 16 + i];
#pragma unroll 8
  for (int k = 0; k < 64; ++k) {
    float xv = xs[k * 65 + r];                   // banks (k+r)%32: 2-way, free
    float4 w0 = Ws4[k * 16 + cg * 4 + 0];        // wave-uniform broadcast
    float4 w1 = Ws4[k * 16 + cg * 4 + 1];
    float4 w2 = Ws4[k * 16 + cg * 4 + 2];
    float4 w3 = Ws4[k * 16 + cg * 4 + 3];
    acc[0]  += xv * w0.x; acc[1]  += xv * w0.y; acc[2]  += xv * w0.z; acc[3]  += xv * w0.w;
    acc[4]  += xv * w1.x; acc[5]  += xv * w1.y; acc[6]  += xv * w1.z; acc[7]  += xv * w1.w;
    acc[8]  += xv * w2.x; acc[9]  += xv * w2.y; acc[10] += xv * w2.z; acc[11] += xv * w2.w;
    acc[12] += xv * w3.x; acc[13] += xv * w3.y; acc[14] += xv * w3.z; acc[15] += xv * w3.w;
  }
#pragma unroll
  for (int i = 0; i < 16; ++i) acc[i] = fmaxf(acc[i], 0.f);
}

// Fused embedding: h1=relu(x@w0+b0); h2=relu(h1@w1+b1) -> A, AT; msg0=relu(h2@wm+bm) -> M
__global__ __launch_bounds__(256) void emb3_kernel(
    const float* __restrict__ x,
    const float* __restrict__ ew0, const float* __restrict__ eb0,
    const float* __restrict__ ew1, const float* __restrict__ eb1,
    const float* __restrict__ wmm, const float* __restrict__ bmm,
    float* __restrict__ outA, float* __restrict__ outAT, float* __restrict__ outM)
{
  const int tid = threadIdx.x;
  const int r = tid & 63, cg = tid >> 6;
  const size_t rowbase = (size_t)blockIdx.x * 64;
  __shared__ float xs[64 * 65];       // transposed: xs[c*65 + row]
  __shared__ float Ws[64 * 64];
  __shared__ float bs[64];
  float acc[16];

#pragma unroll
  for (int i = 0; i < 16; ++i) {
    int idx = tid + 256 * i;
    xs[(idx & 63) * 65 + (idx >> 6)] = x[rowbase * 64 + idx];
    Ws[idx] = ew0[idx];
  }
  if (tid < 64) bs[tid] = eb0[tid];
  __syncthreads();
  mlp_layer(acc, xs, Ws, bs, r, cg);             // h1
  __syncthreads();
#pragma unroll
  for (int i = 0; i < 16; ++i) {
    xs[(cg * 16 + i) * 65 + r] = acc[i];
    Ws[tid + 256 * i] = ew1[tid + 256 * i];
  }
  if (tid < 64) bs[tid] = eb1[tid];
  __syncthreads();
  mlp_layer(acc, xs, Ws, bs, r, cg);             // h2
  {
    float4* o4 = (float4*)(outA + (rowbase + r) * 64 + cg * 16);
#pragma unroll
    for (int q = 0; q < 4; ++q)
      o4[q] = make_float4(acc[q*4+0], acc[q*4+1], acc[q*4+2], acc[q*4+3]);
  }
  __syncthreads();
#pragma unroll
  for (int i = 0; i < 16; ++i) {
    xs[(cg * 16 + i) * 65 + r] = acc[i];
    Ws[tid + 256 * i] = wmm[tid + 256 * i];
  }
  if (tid < 64) bs[tid] = bmm[tid];
  __syncthreads();
  {   // flush AT (h2 transposed, feature-major)
    const size_t bb = rowbase >> 11;
    const int nbase = (int)(rowbase & 2047);
    const int c = tid >> 2, seg = tid & 3;
    float* oT = outAT + bb * 64 * N_NODES + (size_t)c * N_NODES + nbase + seg * 16;
#pragma unroll
    for (int q = 0; q < 4; ++q)
      ((float4*)oT)[q] = make_float4(xs[c*65+seg*16+q*4+0], xs[c*65+seg*16+q*4+1],
                                     xs[c*65+seg*16+q*4+2], xs[c*65+seg*16+q*4+3]);
  }
  mlp_layer(acc, xs, Ws, bs, r, cg);             // msg0
  {
    float4* o4 = (float4*)(outM + (rowbase + r) * 64 + cg * 16);
#pragma unroll
    for (int q = 0; q < 4; ++q)
      o4[q] = make_float4(acc[q*4+0], acc[q*4+1], acc[q*4+2], acc[q*4+3]);
  }
}

// plain single-layer linrelu (msg1)
__global__ __launch_bounds__(256) void linrelu_kernel(
    const float* __restrict__ in, const float* __restrict__ W,
    const float* __restrict__ bias, float* __restrict__ out)
{
  const int tid = threadIdx.x;
  const int r = tid & 63, cg = tid >> 6;
  const size_t rowbase = (size_t)blockIdx.x * 64;
  __shared__ float xs[64 * 65];
  __shared__ float Ws[64 * 64];
  __shared__ float bs[64];
  float acc[16];
#pragma unroll
  for (int i = 0; i < 16; ++i) {
    int idx = tid + 256 * i;
    xs[(idx & 63) * 65 + (idx >> 6)] = in[rowbase * 64 + idx];
    Ws[idx] = W[idx];
  }
  if (tid < 64) bs[tid] = bias[tid];
  __syncthreads();
  mlp_layer(acc, xs, Ws, bs, r, cg);
  float4* o4 = (float4*)(out + (rowbase + r) * 64 + cg * 16);
#pragma unroll
  for (int q = 0; q < 4; ++q)
    o4[q] = make_float4(acc[q*4+0], acc[q*4+1], acc[q*4+2], acc[q*4+3]);
}

// Fused: S = h_tile . h^T (8 rows x 2048): packed-fp32 FMA, float4 coalesced
// columns, SGPR row operands; exact per-row top-50 via L-prefiltered radix
// select (sub-counter histograms); then FINAL dense-masked write or MP epilogue.
template <bool FINAL>
__global__ __launch_bounds__(256, 4) void mp_kernel(
    const float* __restrict__ h, const float* __restrict__ hT,
    const float* __restrict__ msg,
    const float* __restrict__ wu, const float* __restrict__ bu,
    float* __restrict__ outp, float* __restrict__ outT)
{
  const int tid = threadIdx.x;
  const int lane = tid & 63;
  const int w64 = tid >> 6;
  const int bid = blockIdx.x;
  const int b = bid & 7;                  // round-robin blockIdx->XCD: 1 batch/XCD
  const int n0 = (bid >> 3) * 8;

  __shared__ float hrL[8 * 64];           // MP epilogue only
  __shared__ unsigned hist[8][HROW];      // sub-counter radix histograms
  __shared__ unsigned pfxs[8], Kcur[8];
  __shared__ unsigned gtc[8], eqc[8];
  __shared__ unsigned LwS[4][8], Lrow[8];
  __shared__ int seli[8][64];
  __shared__ float selv[8][64];
  __shared__ int eqlist[8][64];
  __shared__ float aggb[8 * 64];
  __shared__ float ot[64 * 9];

  const float* hb  = h  + (size_t)b * N_NODES * 64;
  const float* hTb = hT + (size_t)b * 64 * N_NODES;
  const float* colp = hTb + 4 * tid;

  float4 cur[2], nxt[2];
  cur[0] = *(const float4*)(colp);
  cur[1] = *(const float4*)(colp + 1024);

  if (!FINAL) {
    hrL[tid]       = hb[(size_t)n0 * 64 + tid];
    hrL[tid + 256] = hb[(size_t)n0 * 64 + 256 + tid];
  }
  if (tid < 8) { Kcur[tid] = KSEL; gtc[tid] = 0; eqc[tid] = 0; pfxs[tid] = 0; }
  for (int i = tid; i < 8 * HROW; i += 256) (&hist[0][0])[i] = 0;
  __syncthreads();

  // ---- S tile: af[r*8 + p*4 + e], column m = p*1024 + 4*tid + e
  v2f acc2[32];
#pragma unroll
  for (int i = 0; i < 32; ++i) { acc2[i][0] = 0.f; acc2[i][1] = 0.f; }

  const float* hrow = hb + (size_t)n0 * 64;   // block-uniform -> s_load path

#pragma unroll 2
  for (int k4 = 0; k4 < 16; ++k4) {
    float4 a[8];
#pragma unroll
    for (int r = 0; r < 8; ++r)
      a[r] = *(const float4*)(hrow + r * 64 + k4 * 4);   // uniform scalar loads
#pragma unroll
    for (int kk = 0; kk < 4; ++kk) {
      const int k = k4 * 4 + kk;
      if (k < 63) {                                       // prefetch k+1 columns
        nxt[0] = *(const float4*)(colp + (size_t)(k + 1) * N_NODES);
        nxt[1] = *(const float4*)(colp + (size_t)(k + 1) * N_NODES + 1024);
      }
      v2f c00 = {cur[0].x, cur[0].y}, c01 = {cur[0].z, cur[0].w};
      v2f c10 = {cur[1].x, cur[1].y}, c11 = {cur[1].z, cur[1].w};
#pragma unroll
      for (int r = 0; r < 8; ++r) {
        const float ar = ((const float*)&a[r])[kk];
        v2f as = {ar, ar};
        acc2[r*4+0] = __builtin_elementwise_fma(as, c00, acc2[r*4+0]);
        acc2[r*4+1] = __builtin_elementwise_fma(as, c01, acc2[r*4+1]);
        acc2[r*4+2] = __builtin_elementwise_fma(as, c10, acc2[r*4+2]);
        acc2[r*4+3] = __builtin_elementwise_fma(as, c11, acc2[r*4+3]);
      }
      cur[0] = nxt[0]; cur[1] = nxt[1];
    }
  }

  const float* af = (const float*)acc2;
  unsigned uacc[64];
#pragma unroll
  for (int i = 0; i < 64; ++i) uacc[i] = ford(af[i]);

  // ---- exact prefilter: Lrow[r] = max over waves of (wave-min of lane-max-of-8)
  // guarantees >=64 values >= Lrow <= T; gates all histogram work.
#pragma unroll
  for (int rr = 0; rr < 8; ++rr) {
    unsigned mx = uacc[rr * 8];
#pragma unroll
    for (int j = 1; j < 8; ++j) mx = mx > uacc[rr*8+j] ? mx : uacc[rr*8+j];
#pragma unroll
    for (int off = 32; off >= 1; off >>= 1) {
      unsigned o = (unsigned)__shfl_xor((int)mx, off, 64);
      mx = mx < o ? mx : o;
    }
    if (lane == 0) LwS[w64][rr] = mx;
  }
  __syncthreads();
  if (tid < 8) {
    unsigned a0 = LwS[0][tid], a1 = LwS[1][tid], a2 = LwS[2][tid], a3 = LwS[3][tid];
    unsigned mA = a0 > a1 ? a0 : a1, mB = a2 > a3 ? a2 : a3;
    Lrow[tid] = mA > mB ? mA : mB;
  }
  __syncthreads();

  // ---- radix select, 4x8-bit levels, candidates = {u >= Lrow[r]} (exact)
  const int sub = lane & 1;
  for (int lvl = 0; lvl < 4; ++lvl) {
    const int shift = 24 - 8 * lvl;
#pragma unroll
    for (int r = 0; r < 8; ++r) {
      const unsigned pr = pfxs[r];
      const unsigned Lv = Lrow[r];
      unsigned* hrw = hist[r];
#pragma unroll
      for (int j = 0; j < 8; ++j) {
        unsigned u = uacc[r * 8 + j];
        bool act = (u >= Lv) && (lvl == 0 || ((u >> (shift + 8)) == pr));
        if (act) atomicAdd(&hrw[hidx((u >> shift) & 255u, sub)], 1u);
      }
    }
    __syncthreads();
    {
#pragma unroll
      for (int q = 0; q < 2; ++q) {
        const int rr = w64 * 2 + q;
        unsigned* hrw = hist[rr];
        uint4 q0 = *(const uint4*)&hrw[lane * 8];
        uint4 q1 = *(const uint4*)&hrw[lane * 8 + 4];
        *(uint4*)&hrw[lane * 8]     = make_uint4(0,0,0,0);
        *(uint4*)&hrw[lane * 8 + 4] = make_uint4(0,0,0,0);
        unsigned c0 = q0.x + q0.y, c1 = q0.z + q0.w;
        unsigned c2 = q1.x + q1.y, c3 = q1.z + q1.w;
        unsigned s0 = c0, s1 = c1, s2 = c2, s3 = c3;      // inclusive suffix/lane
#pragma unroll
        for (int off = 1; off < 64; off <<= 1) {
          unsigned t0=__shfl_down((int)s0,off,64), t1=__shfl_down((int)s1,off,64);
          unsigned t2=__shfl_down((int)s2,off,64), t3=__shfl_down((int)s3,off,64);
          if (lane + off < 64) { s0+=t0; s1+=t1; s2+=t2; s3+=t3; }
        }
        unsigned T1=(unsigned)__shfl((int)s1,0,64), T2=(unsigned)__shfl((int)s2,0,64);
        unsigned T3=(unsigned)__shfl((int)s3,0,64);
        unsigned Kc = Kcur[rr];
        unsigned pold = pfxs[rr];
        unsigned A0 = s0 - c0 + T1 + T2 + T3;   // count in bins > (g,lane)
        unsigned A1 = s1 - c1 + T2 + T3;
        unsigned A2 = s2 - c2 + T3;
        unsigned A3 = s3 - c3;
        if (A0 < Kc && Kc <= A0 + c0) { Kcur[rr]=Kc-A0; pfxs[rr]=(pold<<8)|(unsigned)(0*64+lane); }
        if (A1 < Kc && Kc <= A1 + c1) { Kcur[rr]=Kc-A1; pfxs[rr]=(pold<<8)|(unsigned)(1*64+lane); }
        if (A2 < Kc && Kc <= A2 + c2) { Kcur[rr]=Kc-A2; pfxs[rr]=(pold<<8)|(unsigned)(2*64+lane); }
        if (A3 < Kc && Kc <= A3 + c3) { Kcur[rr]=Kc-A3; pfxs[rr]=(pold<<8)|(unsigned)(3*64+lane); }
      }
    }
    __syncthreads();
  }

  // ---- extract winners (> T) and tie candidates (== T)
#pragma unroll
  for (int r = 0; r < 8; ++r) {
    const unsigned T = pfxs[r];
#pragma unroll
    for (int j = 0; j < 8; ++j) {
      const unsigned u = uacc[r * 8 + j];
      const int m = (j >> 2) * 1024 + 4 * tid + (j & 3);
      if (u > T) {
        unsigned pos = atomicAdd(&gtc[r], 1u);
        seli[r][pos] = m; selv[r][pos] = funord(u);
      } else if (u == T) {
        unsigned pos = atomicAdd(&eqc[r], 1u);
        if (pos < 64) eqlist[r][pos] = m;
      }
    }
  }
  __syncthreads();

  // ---- resolve ties: `need` smallest indices among equals (jax order)
  if (tid < 8) {
    const int r = tid;
    const int g = (int)gtc[r];
    const int need = KSEL - g;
    const int e = (eqc[r] < 64u) ? (int)eqc[r] : 64;
    const float Tf = funord(pfxs[r]);
    for (int t = 0; t < need; ++t) {
      int bestp = -1, bestm = 0x7FFFFFFF;
      for (int i = 0; i < e; ++i) {
        int mm = eqlist[r][i];
        if (mm < bestm) { bestm = mm; bestp = i; }
      }
      if (bestp < 0) break;
      eqlist[r][bestp] = 0x7FFFFFFF;
      seli[r][g + t] = bestm;
      selv[r][g + t] = Tf;
    }
  }
  __syncthreads();

  if constexpr (FINAL) {
    float* ob = outp + ((size_t)b * N_NODES + n0) * N_NODES;
#pragma unroll
    for (int r = 0; r < 8; ++r) {
      const unsigned T = pfxs[r];
      const int g = (int)gtc[r];
      const int need = KSEL - g;
#pragma unroll
      for (int p = 0; p < 2; ++p) {
        float4 w; float* wf = (float*)&w;
#pragma unroll
        for (int e = 0; e < 4; ++e) {
          const unsigned u = uacc[r * 8 + p * 4 + e];
          const int m = p * 1024 + 4 * tid + e;
          bool keep = u > T;
          if (u == T) {
            for (int i = 0; i < need; ++i)
              if (seli[r][g + i] == m) { keep = true; break; }
          }
          wf[e] = keep ? funord(u) : 0.f;
        }
        *(float4*)(ob + (size_t)r * N_NODES + p * 1024 + 4 * tid) = w;
      }
    }
  } else {
    // sparse aggregation: agg[r][:] = sum_i v_i * msg[m_i][:]
    const int r = tid >> 5;
    const int ln = tid & 31;
    const float* msgb = msg + (size_t)b * N_NODES * 64;
    float a0 = 0.f, a1 = 0.f;
    for (int i = 0; i < KSEL; ++i) {
      int mi = seli[r][i];
      float vv = selv[r][i];
      const float* mr = msgb + (size_t)mi * 64;
      a0 += vv * mr[ln];
      a1 += vv * mr[ln + 32];
    }
    aggb[r * 64 + ln] = a0;
    aggb[r * 64 + ln + 32] = a1;
    __syncthreads();
    float s0 = bu[ln], s1 = bu[ln + 32];
#pragma unroll 8
    for (int jj = 0; jj < 64; ++jj) {
      float hv = hrL[r * 64 + jj];
      s0 += hv * wu[jj * 64 + ln];
      s1 += hv * wu[jj * 64 + ln + 32];
    }
#pragma unroll 8
    for (int jj = 0; jj < 64; ++jj) {
      float av = aggb[r * 64 + jj];
      s0 += av * wu[(64 + jj) * 64 + ln];
      s1 += av * wu[(64 + jj) * 64 + ln + 32];
    }
    s0 = fmaxf(s0, 0.f); s1 = fmaxf(s1, 0.f);
    float* o = outp + ((size_t)b * N_NODES + n0 + r) * 64;
    o[ln] = s0;
    o[ln + 32] = s1;
    ot[ln * 9 + r] = s0;                 // bank (9f+r)%32: conflict-free
    ot[(ln + 32) * 9 + r] = s1;
    __syncthreads();
    for (int i = tid; i < 512; i += 256) { // flush h2T (32B segments)
      int f = i >> 3, rr = i & 7;
      outT[(size_t)b * 64 * N_NODES + (size_t)f * N_NODES + n0 + rr] = ot[f * 9 + rr];
    }
  }
}

extern "C" void kernel_launch(void* const* d_in, const int* in_sizes, int n_in,
                              void* d_out, int out_size, void* d_ws, size_t ws_size,
                              hipStream_t stream)
{
  (void)in_sizes; (void)n_in; (void)out_size; (void)ws_size;
  const float* x   = (const float*)d_in[0];
  const float* ew0 = (const float*)d_in[1];
  const float* eb0 = (const float*)d_in[2];
  const float* ew1 = (const float*)d_in[3];
  const float* eb1 = (const float*)d_in[4];
  const float* w0m = (const float*)d_in[5];
  const float* b0m = (const float*)d_in[6];
  const float* w0u = (const float*)d_in[7];
  const float* b0u = (const float*)d_in[8];
  const float* w1m = (const float*)d_in[9];
  const float* b1m = (const float*)d_in[10];
  const float* w1u = (const float*)d_in[11];
  const float* b1u = (const float*)d_in[12];
  float* out = (float*)d_out;
  float* ws = (float*)d_ws;

  const size_t BUF = (size_t)8 * N_NODES * 64;  // 4 MB each, 20 MB total
  float* A   = ws;
  float* AT  = ws + 1 * BUF;
  float* Bf  = ws + 2 * BUF;
  float* BfT = ws + 3 * BUF;
  float* C   = ws + 4 * BUF;

  // fused embedding (2 layers) + msg0
  emb3_kernel<<<256, 256, 0, stream>>>(x, ew0, eb0, ew1, eb1, w0m, b0m, A, AT, C);

  // MP layer 0 (consumes msg0=C, produces Bf/BfT)
  mp_kernel<false><<<2048, 256, 0, stream>>>(A, AT, C, w0u, b0u, Bf, BfT);

  // msg1
  linrelu_kernel<<<256, 256, 0, stream>>>(Bf, w1m, b1m, C);

  // MP layer 1
  mp_kernel<false><<<2048, 256, 0, stream>>>(Bf, BfT, C, w1u, b1u, A, AT);

  // final dense top-k adjacency
  mp_kernel<true><<<2048, 256, 0, stream>>>(A, AT, nullptr, nullptr, nullptr, out, nullptr);
}